// Round 7
// baseline (879.412 us; speedup 1.0000x reference)
//
#include <hip/hip_runtime.h>
#include <hip/hip_fp16.h>
#include <math.h>

#define FIN 512
#define FH 16
#define FOUT 40
#define RANGE 128        // dst nodes per bucket
#define RSH 7
#define NB_MAX 1024      // supports n <= 131072 (also the 17-bit src pack limit)
#define SRC_BITS 17
#define SRC_MASK 0x1FFFF
#define BCHUNK 4096      // edges per bin_k block
#define HCHUNK 16384     // edges per histA block
#define AP 17            // padded acc row stride (banks spread)
#define GCHUNK 4096      // edges per gather chunk (512 thr x 8 deep)

// ---------- bucket histogram: bcnt[b] = #edges with dst in bucket b ----------
__global__ __launch_bounds__(256) void histA_k(const int* __restrict__ dst, int E, int NB,
                                               unsigned* __restrict__ bcnt) {
  __shared__ unsigned h[NB_MAX];
  for (int b = threadIdx.x; b < NB; b += 256) h[b] = 0;
  __syncthreads();
  const int base = blockIdx.x * HCHUNK;
  const int cn = min(HCHUNK, E - base);
  for (int u = threadIdx.x; u < cn; u += 256)
    atomicAdd(&h[((unsigned)dst[base + u]) >> RSH], 1u);
  __syncthreads();
  for (int b = threadIdx.x; b < NB; b += 256) {
    unsigned c = h[b];
    if (c) atomicAdd(&bcnt[b], c);
  }
}

// ---------- exclusive scan of bucket counts (NB <= 1024, one block) ----------
__global__ __launch_bounds__(1024) void scanB_k(const unsigned* __restrict__ bcnt, int NB,
                                                unsigned* __restrict__ boff,
                                                unsigned* __restrict__ bcur) {
  __shared__ unsigned ws[16];
  const int t = threadIdx.x, lane = t & 63, wid = t >> 6;
  unsigned v = (t < NB) ? bcnt[t] : 0;
  unsigned incl = v;
#pragma unroll
  for (int d = 1; d < 64; d <<= 1) {
    unsigned o = __shfl_up(incl, d);
    if (lane >= d) incl += o;
  }
  if (lane == 63) ws[wid] = incl;
  __syncthreads();
  unsigned woff = 0, tot = 0;
#pragma unroll
  for (int w = 0; w < 16; ++w) {
    unsigned s = ws[w];
    if (w < wid) woff += s;
    tot += s;
  }
  unsigned ex = woff + incl - v;
  if (t < NB) { boff[t] = ex; bcur[t] = ex; }
  if (t == 0) boff[NB] = tot;
}

// ---------- bin edges by bucket: chunk-local counting sort, coalesced flush ----------
__global__ __launch_bounds__(256) void bin_k(const int* __restrict__ src,
                                             const int* __restrict__ dst, int E, int NB,
                                             unsigned* __restrict__ bcur,
                                             unsigned* __restrict__ bins) {
  __shared__ unsigned hist[NB_MAX];
  __shared__ unsigned excl[NB_MAX];
  __shared__ unsigned gbase[NB_MAX];
  __shared__ unsigned lcur[NB_MAX];
  __shared__ unsigned stage[BCHUNK];
  __shared__ unsigned short sbkt[BCHUNK];
  __shared__ unsigned wtot[4];
  const int t = threadIdx.x, lane = t & 63, wid = t >> 6;
  for (int b = t; b < NB; b += 256) hist[b] = 0;
  __syncthreads();
  const int base = blockIdx.x * BCHUNK;
  const int cn = min(BCHUNK, E - base);
  for (int u = t; u < cn; u += 256)
    atomicAdd(&hist[((unsigned)dst[base + u]) >> RSH], 1u);
  __syncthreads();
  // block-wide exclusive scan of hist[0..NB)
  unsigned loc[4], s = 0;
#pragma unroll
  for (int j = 0; j < 4; ++j) {
    int idx = t * 4 + j;
    loc[j] = s;
    s += (idx < NB) ? hist[idx] : 0;
  }
  unsigned incl = s;
#pragma unroll
  for (int d = 1; d < 64; d <<= 1) {
    unsigned o = __shfl_up(incl, d);
    if (lane >= d) incl += o;
  }
  if (lane == 63) wtot[wid] = incl;
  __syncthreads();
  unsigned woff = 0;
  for (int w = 0; w < wid; ++w) woff += wtot[w];
  unsigned tex = woff + incl - s;
#pragma unroll
  for (int j = 0; j < 4; ++j) {
    int idx = t * 4 + j;
    if (idx < NB) excl[idx] = tex + loc[j];
  }
  __syncthreads();
  for (int b = t; b < NB; b += 256) {
    unsigned c = hist[b];
    gbase[b] = c ? atomicAdd(&bcur[b], c) : 0u;
    lcur[b] = excl[b];
  }
  __syncthreads();
  for (int u = t; u < cn; u += 256) {
    int e = base + u;
    unsigned d = (unsigned)dst[e];
    unsigned bkt = d >> RSH;
    unsigned pk = ((unsigned)src[e]) | ((d & (RANGE - 1)) << SRC_BITS);
    unsigned lr = atomicAdd(&lcur[bkt], 1u);
    stage[lr] = pk;
    sbkt[lr] = (unsigned short)bkt;
  }
  __syncthreads();
  for (int u = t; u < cn; u += 256) {
    unsigned bkt = sbkt[u];
    bins[gbase[bkt] + (u - excl[bkt])] = stage[u];
  }
}

// ---------- per-node degree -> dinv, from binned edges (LDS histogram) ----------
__global__ __launch_bounds__(256) void deg_k(const unsigned* __restrict__ boff,
                                             const unsigned* __restrict__ bins, int n,
                                             float* __restrict__ dinv) {
  __shared__ unsigned dh[RANGE];
  const int t = threadIdx.x, b = blockIdx.x;
  if (t < RANGE) dh[t] = 0;
  __syncthreads();
  const unsigned jb = boff[b], je = boff[b + 1];
  for (unsigned j = jb + t; j < je; j += 256) atomicAdd(&dh[bins[j] >> SRC_BITS], 1u);
  __syncthreads();
  const int i = b * RANGE + t;
  if (t < RANGE && i < n) dinv[i] = rsqrtf((float)dh[t] + 1.0f);
}

// ---------------- hs1 = (x @ W1) * dinv[row], stored fp16 ----------------
__global__ __launch_bounds__(256) void gemm1_k(const float* __restrict__ x,
                                               const float* __restrict__ W1,
                                               const float* __restrict__ dinv, int n,
                                               __half* __restrict__ hs1) {
  __shared__ float w1s[FIN * FH];  // 32 KiB
  for (int idx = threadIdx.x; idx < FIN * FH; idx += 256) w1s[idx] = W1[idx];
  __syncthreads();

  const int row_raw = blockIdx.x * 256 + threadIdx.x;
  const int row = row_raw < n ? row_raw : n - 1;
  const float4* __restrict__ xr = (const float4*)(x + (size_t)row * FIN);

  float4 a0 = {0, 0, 0, 0}, a1 = {0, 0, 0, 0}, a2 = {0, 0, 0, 0}, a3 = {0, 0, 0, 0};

#pragma unroll 2
  for (int it = 0; it < FIN / 4; ++it) {
    float4 xv = xr[it];
    const float* wf = w1s + it * 4 * FH;
#pragma unroll
    for (int j = 0; j < 4; ++j) {
      const float xj = (j == 0) ? xv.x : (j == 1) ? xv.y : (j == 2) ? xv.z : xv.w;
      const float* wj = wf + j * FH;
      float4 w0 = *(const float4*)(wj + 0);
      float4 w1 = *(const float4*)(wj + 4);
      float4 w2 = *(const float4*)(wj + 8);
      float4 w3 = *(const float4*)(wj + 12);
      a0.x += xj * w0.x; a0.y += xj * w0.y; a0.z += xj * w0.z; a0.w += xj * w0.w;
      a1.x += xj * w1.x; a1.y += xj * w1.y; a1.z += xj * w1.z; a1.w += xj * w1.w;
      a2.x += xj * w2.x; a2.y += xj * w2.y; a2.z += xj * w2.z; a2.w += xj * w2.w;
      a3.x += xj * w3.x; a3.y += xj * w3.y; a3.z += xj * w3.z; a3.w += xj * w3.w;
    }
  }

  if (row_raw < n) {
    const float di = dinv[row];
    __half2 hb[8];
    hb[0] = __floats2half2_rn(a0.x * di, a0.y * di);
    hb[1] = __floats2half2_rn(a0.z * di, a0.w * di);
    hb[2] = __floats2half2_rn(a1.x * di, a1.y * di);
    hb[3] = __floats2half2_rn(a1.z * di, a1.w * di);
    hb[4] = __floats2half2_rn(a2.x * di, a2.y * di);
    hb[5] = __floats2half2_rn(a2.z * di, a2.w * di);
    hb[6] = __floats2half2_rn(a3.x * di, a3.y * di);
    hb[7] = __floats2half2_rn(a3.z * di, a3.w * di);
    uint4* o = (uint4*)(hs1 + (size_t)row * FH);
    o[0] = ((const uint4*)hb)[0];
    o[1] = ((const uint4*)hb)[1];
  }
}

// ---- accumulate one fp16 row (2x uint4) into padded LDS acc row ----
__device__ __forceinline__ void accum_row(float* __restrict__ arow, uint4 q0, uint4 q1) {
  float2 f;
  f = __half22float2(*(const __half2*)&q0.x); atomicAdd(arow + 0, f.x);  atomicAdd(arow + 1, f.y);
  f = __half22float2(*(const __half2*)&q0.y); atomicAdd(arow + 2, f.x);  atomicAdd(arow + 3, f.y);
  f = __half22float2(*(const __half2*)&q0.z); atomicAdd(arow + 4, f.x);  atomicAdd(arow + 5, f.y);
  f = __half22float2(*(const __half2*)&q0.w); atomicAdd(arow + 6, f.x);  atomicAdd(arow + 7, f.y);
  f = __half22float2(*(const __half2*)&q1.x); atomicAdd(arow + 8, f.x);  atomicAdd(arow + 9, f.y);
  f = __half22float2(*(const __half2*)&q1.y); atomicAdd(arow + 10, f.x); atomicAdd(arow + 11, f.y);
  f = __half22float2(*(const __half2*)&q1.z); atomicAdd(arow + 12, f.x); atomicAdd(arow + 13, f.y);
  f = __half22float2(*(const __half2*)&q1.w); atomicAdd(arow + 14, f.x); atomicAdd(arow + 15, f.y);
}

// 8-edge-deep batched edge phase. All loads issued before any use; register
// arrays fully unrolled (static indexing only). __launch_bounds__(512,4)
// gives a 128-VGPR budget so the 16 row loads stay in flight (MLP fix).
__device__ __forceinline__ void edge_phase(const __half* __restrict__ tab,
                                           const unsigned* __restrict__ bins,
                                           unsigned jb, unsigned je, int t,
                                           float* __restrict__ acc) {
  for (unsigned cb = jb; cb < je; cb += GCHUNK) {
    const unsigned j0 = cb + t;
    unsigned pk[8];
    bool val[8];
#pragma unroll
    for (int i = 0; i < 8; ++i) {
      const unsigned j = j0 + i * 512;
      val[i] = (j < je);
      pk[i] = val[i] ? bins[j] : 0u;   // row 0 is a valid dummy
    }
    uint4 q0[8], q1[8];
#pragma unroll
    for (int i = 0; i < 8; ++i) {
      const uint4* rp = (const uint4*)(tab + (size_t)(pk[i] & SRC_MASK) * FH);
      q0[i] = rp[0];
      q1[i] = rp[1];
    }
#pragma unroll
    for (int i = 0; i < 8; ++i) {
      if (val[i]) accum_row(acc + (pk[i] >> SRC_BITS) * AP, q0[i], q1[i]);
    }
  }
}

// ---------- layer-1 gather: 8-deep batched lane-per-edge ----------
__global__ __launch_bounds__(512, 4) void gather1_k(const __half* __restrict__ hs1,
                                                    const unsigned* __restrict__ boff,
                                                    const unsigned* __restrict__ bins,
                                                    const float* __restrict__ dinv,
                                                    const float* __restrict__ b1, int n,
                                                    __half* __restrict__ rs) {
  __shared__ float acc[RANGE * AP];  // 8.7 KiB
  __shared__ float b1s[FH];
  const int t = threadIdx.x, b = blockIdx.x;
  if (t < FH) b1s[t] = b1[t];
  for (int u = t; u < RANGE * AP; u += 512) acc[u] = 0.f;
  __syncthreads();
  const unsigned jb = boff[b], je = boff[b + 1];
  edge_phase(hs1, bins, jb, je, t, acc);
  __syncthreads();
  const int base = b * RANGE;
  {
    const int node = t >> 2, sub = t & 3;  // 512 threads -> 128 nodes x 4 chunks
    const int i = base + node;
    if (i < n) {
      const float* arow = acc + node * AP + sub * 4;
      const float a0 = arow[0], a1 = arow[1], a2 = arow[2], a3 = arow[3];
      const __half2* hp = (const __half2*)(hs1 + (size_t)i * FH + sub * 4);
      const float2 h0 = __half22float2(hp[0]);
      const float2 h1 = __half22float2(hp[1]);
      const float d = dinv[i];
      float r0 = (a0 + h0.x) * d + b1s[sub * 4 + 0];
      float r1 = (a1 + h0.y) * d + b1s[sub * 4 + 1];
      float r2 = (a2 + h1.x) * d + b1s[sub * 4 + 2];
      float r3 = (a3 + h1.y) * d + b1s[sub * 4 + 3];
      r0 = fmaxf(r0, 0.f) * d;
      r1 = fmaxf(r1, 0.f) * d;
      r2 = fmaxf(r2, 0.f) * d;
      r3 = fmaxf(r3, 0.f) * d;
      __half2* rp = (__half2*)(rs + (size_t)i * FH + sub * 4);
      rp[0] = __floats2half2_rn(r0, r1);
      rp[1] = __floats2half2_rn(r2, r3);
    }
  }
}

// ---- layer-2: 8-deep batched gather + W2 matvec + b2 + log_softmax ----
__global__ __launch_bounds__(512, 4) void gather2_k(const __half* __restrict__ rs,
                                                    const unsigned* __restrict__ boff,
                                                    const unsigned* __restrict__ bins,
                                                    const float* __restrict__ dinv,
                                                    const float* __restrict__ W2,
                                                    const float* __restrict__ b2, int n,
                                                    float* __restrict__ out) {
  __shared__ float acc[RANGE * AP];           // 8.7 KiB
  __shared__ float w2s[FH * FOUT + FOUT];     // W2 then b2
  const int t = threadIdx.x, b = blockIdx.x;
  for (int idx = t; idx < FH * FOUT + FOUT; idx += 512)
    w2s[idx] = (idx < FH * FOUT) ? W2[idx] : b2[idx - FH * FOUT];
  for (int u = t; u < RANGE * AP; u += 512) acc[u] = 0.f;
  __syncthreads();
  const unsigned jb = boff[b], je = boff[b + 1];
  edge_phase(rs, bins, jb, je, t, acc);
  __syncthreads();
  const int base = b * RANGE;
  // phase 1: acc = (acc + rs_self) * dinv
  {
    const int node = t >> 2, sub = t & 3;
    const int i = base + node;
    if (i < n) {
      float* arow = acc + node * AP + sub * 4;
      const __half2* rp = (const __half2*)(rs + (size_t)i * FH + sub * 4);
      const float2 r0 = __half22float2(rp[0]);
      const float2 r1 = __half22float2(rp[1]);
      const float d = dinv[i];
      arow[0] = (arow[0] + r0.x) * d;
      arow[1] = (arow[1] + r0.y) * d;
      arow[2] = (arow[2] + r1.x) * d;
      arow[3] = (arow[3] + r1.y) * d;
    }
  }
  __syncthreads();
  // phase 2: per-node 16->40 matvec + log_softmax (8 waves, nodes round-robin)
  const int lane = t & 63, wv = t >> 6;
  for (int nd = wv; nd < RANGE; nd += 8) {
    const int i = base + nd;
    if (i >= n) continue;
    float hv = (lane < FOUT) ? w2s[FH * FOUT + lane] : 0.f;
#pragma unroll
    for (int kk = 0; kk < 16; ++kk) {
      const float a = acc[nd * AP + kk];  // LDS broadcast
      if (lane < FOUT) hv += a * w2s[kk * FOUT + lane];
    }
    float m = (lane < FOUT) ? hv : -INFINITY;
#pragma unroll
    for (int d = 1; d < 64; d <<= 1) m = fmaxf(m, __shfl_xor(m, d));
    float ex = (lane < FOUT) ? expf(hv - m) : 0.f;
#pragma unroll
    for (int d = 1; d < 64; d <<= 1) ex += __shfl_xor(ex, d);
    if (lane < FOUT) out[(size_t)i * FOUT + lane] = hv - m - logf(ex);
  }
}

// ---------------- launch ----------------
extern "C" void kernel_launch(void* const* d_in, const int* in_sizes, int n_in,
                              void* d_out, int out_size, void* d_ws, size_t ws_size,
                              hipStream_t stream) {
  const float* x  = (const float*)d_in[0];
  const int*   ei = (const int*)d_in[1];
  const float* W1 = (const float*)d_in[2];
  const float* b1 = (const float*)d_in[3];
  const float* W2 = (const float*)d_in[4];
  const float* b2 = (const float*)d_in[5];
  float* out = (float*)d_out;

  const int n = in_sizes[0] / FIN;
  const int E = in_sizes[1] / 2;
  const int* src = ei;
  const int* dst = ei + E;
  const int NB = (n + RANGE - 1) >> RSH;

  char* ws = (char*)d_ws;
  size_t o = 0;
  auto alloc = [&](size_t bytes) {
    void* p = ws + o;
    o = (o + bytes + 255) & ~(size_t)255;
    return p;
  };
  unsigned* bcnt = (unsigned*)alloc((size_t)(NB + 1) * 4);
  unsigned* boff = (unsigned*)alloc((size_t)(NB + 1) * 4);
  unsigned* bcur = (unsigned*)alloc((size_t)NB * 4);
  float*    dinv = (float*)alloc((size_t)n * 4);
  unsigned* bins = (unsigned*)alloc((size_t)E * 4);
  __half*   hs1  = (__half*)alloc((size_t)n * FH * 2);
  __half*   rsb  = (__half*)alloc((size_t)n * FH * 2);

  hipMemsetAsync(bcnt, 0, (size_t)(NB + 1) * 4, stream);

  histA_k<<<(E + HCHUNK - 1) / HCHUNK, 256, 0, stream>>>(dst, E, NB, bcnt);
  scanB_k<<<1, 1024, 0, stream>>>(bcnt, NB, boff, bcur);
  bin_k<<<(E + BCHUNK - 1) / BCHUNK, 256, 0, stream>>>(src, dst, E, NB, bcur, bins);
  deg_k<<<NB, 256, 0, stream>>>(boff, bins, n, dinv);

  gemm1_k<<<(n + 255) / 256, 256, 0, stream>>>(x, W1, dinv, n, hs1);
  gather1_k<<<NB, 512, 0, stream>>>(hs1, boff, bins, dinv, b1, n, rsb);
  gather2_k<<<NB, 512, 0, stream>>>(rsb, boff, bins, dinv, W2, b2, n, out);
}

// Round 8
// 868.577 us; speedup vs baseline: 1.0125x; 1.0125x over previous
//
#include <hip/hip_runtime.h>
#include <hip/hip_fp16.h>
#include <math.h>

#define FIN 512
#define FH 16
#define FOUT 40
#define RANGE 128        // dst nodes per bucket
#define RSH 7
#define NB_MAX 1024      // supports n <= 131072 (also the 17-bit src pack limit)
#define SRC_BITS 17
#define SRC_MASK 0x1FFFF
#define BCHUNK 4096      // edges per bin_k block
#define HCHUNK 16384     // edges per histA block
#define AP 17            // padded acc row stride (banks spread)
#define WED 128          // edges staged per wave per round (4 x 32)

typedef unsigned int u32;

// async gather: per-lane random global 16B -> wave-linear LDS (no dest VGPR)
__device__ __forceinline__ void gload_lds16(const void* g, void* l) {
  __builtin_amdgcn_global_load_lds((const __attribute__((address_space(1))) u32*)g,
                                   (__attribute__((address_space(3))) u32*)l, 16, 0, 0);
}

// ---------- bucket histogram: bcnt[b] = #edges with dst in bucket b ----------
__global__ __launch_bounds__(256) void histA_k(const int* __restrict__ dst, int E, int NB,
                                               unsigned* __restrict__ bcnt) {
  __shared__ unsigned h[NB_MAX];
  for (int b = threadIdx.x; b < NB; b += 256) h[b] = 0;
  __syncthreads();
  const int base = blockIdx.x * HCHUNK;
  const int cn = min(HCHUNK, E - base);
  for (int u = threadIdx.x; u < cn; u += 256)
    atomicAdd(&h[((unsigned)dst[base + u]) >> RSH], 1u);
  __syncthreads();
  for (int b = threadIdx.x; b < NB; b += 256) {
    unsigned c = h[b];
    if (c) atomicAdd(&bcnt[b], c);
  }
}

// ---------- exclusive scan of bucket counts (NB <= 1024, one block) ----------
__global__ __launch_bounds__(1024) void scanB_k(const unsigned* __restrict__ bcnt, int NB,
                                                unsigned* __restrict__ boff,
                                                unsigned* __restrict__ bcur) {
  __shared__ unsigned ws[16];
  const int t = threadIdx.x, lane = t & 63, wid = t >> 6;
  unsigned v = (t < NB) ? bcnt[t] : 0;
  unsigned incl = v;
#pragma unroll
  for (int d = 1; d < 64; d <<= 1) {
    unsigned o = __shfl_up(incl, d);
    if (lane >= d) incl += o;
  }
  if (lane == 63) ws[wid] = incl;
  __syncthreads();
  unsigned woff = 0, tot = 0;
#pragma unroll
  for (int w = 0; w < 16; ++w) {
    unsigned s = ws[w];
    if (w < wid) woff += s;
    tot += s;
  }
  unsigned ex = woff + incl - v;
  if (t < NB) { boff[t] = ex; bcur[t] = ex; }
  if (t == 0) boff[NB] = tot;
}

// ---------- bin edges by bucket: chunk-local counting sort, coalesced flush ----------
__global__ __launch_bounds__(256) void bin_k(const int* __restrict__ src,
                                             const int* __restrict__ dst, int E, int NB,
                                             unsigned* __restrict__ bcur,
                                             unsigned* __restrict__ bins) {
  __shared__ unsigned hist[NB_MAX];
  __shared__ unsigned excl[NB_MAX];
  __shared__ unsigned gbase[NB_MAX];
  __shared__ unsigned lcur[NB_MAX];
  __shared__ unsigned stage[BCHUNK];
  __shared__ unsigned short sbkt[BCHUNK];
  __shared__ unsigned wtot[4];
  const int t = threadIdx.x, lane = t & 63, wid = t >> 6;
  for (int b = t; b < NB; b += 256) hist[b] = 0;
  __syncthreads();
  const int base = blockIdx.x * BCHUNK;
  const int cn = min(BCHUNK, E - base);
  for (int u = t; u < cn; u += 256)
    atomicAdd(&hist[((unsigned)dst[base + u]) >> RSH], 1u);
  __syncthreads();
  // block-wide exclusive scan of hist[0..NB)
  unsigned loc[4], s = 0;
#pragma unroll
  for (int j = 0; j < 4; ++j) {
    int idx = t * 4 + j;
    loc[j] = s;
    s += (idx < NB) ? hist[idx] : 0;
  }
  unsigned incl = s;
#pragma unroll
  for (int d = 1; d < 64; d <<= 1) {
    unsigned o = __shfl_up(incl, d);
    if (lane >= d) incl += o;
  }
  if (lane == 63) wtot[wid] = incl;
  __syncthreads();
  unsigned woff = 0;
  for (int w = 0; w < wid; ++w) woff += wtot[w];
  unsigned tex = woff + incl - s;
#pragma unroll
  for (int j = 0; j < 4; ++j) {
    int idx = t * 4 + j;
    if (idx < NB) excl[idx] = tex + loc[j];
  }
  __syncthreads();
  for (int b = t; b < NB; b += 256) {
    unsigned c = hist[b];
    gbase[b] = c ? atomicAdd(&bcur[b], c) : 0u;
    lcur[b] = excl[b];
  }
  __syncthreads();
  for (int u = t; u < cn; u += 256) {
    int e = base + u;
    unsigned d = (unsigned)dst[e];
    unsigned bkt = d >> RSH;
    unsigned pk = ((unsigned)src[e]) | ((d & (RANGE - 1)) << SRC_BITS);
    unsigned lr = atomicAdd(&lcur[bkt], 1u);
    stage[lr] = pk;
    sbkt[lr] = (unsigned short)bkt;
  }
  __syncthreads();
  for (int u = t; u < cn; u += 256) {
    unsigned bkt = sbkt[u];
    bins[gbase[bkt] + (u - excl[bkt])] = stage[u];
  }
}

// ---------- per-node degree -> dinv, from binned edges (LDS histogram) ----------
__global__ __launch_bounds__(256) void deg_k(const unsigned* __restrict__ boff,
                                             const unsigned* __restrict__ bins, int n,
                                             float* __restrict__ dinv) {
  __shared__ unsigned dh[RANGE];
  const int t = threadIdx.x, b = blockIdx.x;
  if (t < RANGE) dh[t] = 0;
  __syncthreads();
  const unsigned jb = boff[b], je = boff[b + 1];
  for (unsigned j = jb + t; j < je; j += 256) atomicAdd(&dh[bins[j] >> SRC_BITS], 1u);
  __syncthreads();
  const int i = b * RANGE + t;
  if (t < RANGE && i < n) dinv[i] = rsqrtf((float)dh[t] + 1.0f);
}

// ---------------- hs1 = (x @ W1) * dinv[row], stored fp16 ----------------
__global__ __launch_bounds__(256) void gemm1_k(const float* __restrict__ x,
                                               const float* __restrict__ W1,
                                               const float* __restrict__ dinv, int n,
                                               __half* __restrict__ hs1) {
  __shared__ float w1s[FIN * FH];  // 32 KiB
  for (int idx = threadIdx.x; idx < FIN * FH; idx += 256) w1s[idx] = W1[idx];
  __syncthreads();

  const int row_raw = blockIdx.x * 256 + threadIdx.x;
  const int row = row_raw < n ? row_raw : n - 1;
  const float4* __restrict__ xr = (const float4*)(x + (size_t)row * FIN);

  float4 a0 = {0, 0, 0, 0}, a1 = {0, 0, 0, 0}, a2 = {0, 0, 0, 0}, a3 = {0, 0, 0, 0};

#pragma unroll 2
  for (int it = 0; it < FIN / 4; ++it) {
    float4 xv = xr[it];
    const float* wf = w1s + it * 4 * FH;
#pragma unroll
    for (int j = 0; j < 4; ++j) {
      const float xj = (j == 0) ? xv.x : (j == 1) ? xv.y : (j == 2) ? xv.z : xv.w;
      const float* wj = wf + j * FH;
      float4 w0 = *(const float4*)(wj + 0);
      float4 w1 = *(const float4*)(wj + 4);
      float4 w2 = *(const float4*)(wj + 8);
      float4 w3 = *(const float4*)(wj + 12);
      a0.x += xj * w0.x; a0.y += xj * w0.y; a0.z += xj * w0.z; a0.w += xj * w0.w;
      a1.x += xj * w1.x; a1.y += xj * w1.y; a1.z += xj * w1.z; a1.w += xj * w1.w;
      a2.x += xj * w2.x; a2.y += xj * w2.y; a2.z += xj * w2.z; a2.w += xj * w2.w;
      a3.x += xj * w3.x; a3.y += xj * w3.y; a3.z += xj * w3.z; a3.w += xj * w3.w;
    }
  }

  if (row_raw < n) {
    const float di = dinv[row];
    __half2 hb[8];
    hb[0] = __floats2half2_rn(a0.x * di, a0.y * di);
    hb[1] = __floats2half2_rn(a0.z * di, a0.w * di);
    hb[2] = __floats2half2_rn(a1.x * di, a1.y * di);
    hb[3] = __floats2half2_rn(a1.z * di, a1.w * di);
    hb[4] = __floats2half2_rn(a2.x * di, a2.y * di);
    hb[5] = __floats2half2_rn(a2.z * di, a2.w * di);
    hb[6] = __floats2half2_rn(a3.x * di, a3.y * di);
    hb[7] = __floats2half2_rn(a3.z * di, a3.w * di);
    uint4* o = (uint4*)(hs1 + (size_t)row * FH);
    o[0] = ((const uint4*)hb)[0];
    o[1] = ((const uint4*)hb)[1];
  }
}

// ---- async edge phase: gather rows to wave-private LDS stage, then accumulate ----
// Per round: 32 edges/wave, 2 lanes per edge (16B halves). 4 rounds issued async
// (global_load_lds has no dest VGPR -> compiler cannot serialize), one vmcnt(0)
// per 128 edges. pk stays in this lane's registers (same lane<->edge map on
// stage and consume).
__device__ __forceinline__ void edge_phase(const __half* __restrict__ tab,
                                           const unsigned* __restrict__ bins,
                                           unsigned jb, unsigned je, int t,
                                           __half* __restrict__ stage,
                                           float* __restrict__ acc) {
  const int l = t & 63, wv = t >> 6;
  __half* swv = stage + wv * (WED * FH);  // 128 edges * 16 halfs = 4 KiB
  for (unsigned c = jb + (unsigned)wv * WED; c < je; c += 8u * WED) {
    unsigned pk[4];
    bool vld[4];
#pragma unroll
    for (int r = 0; r < 4; ++r) {
      const unsigned e = c + r * 32u + (unsigned)(l >> 1);
      vld[r] = (e < je);
      pk[r] = bins[vld[r] ? e : (je - 1)];
      const unsigned row = vld[r] ? (pk[r] & SRC_MASK) : 0u;
      const __half* g = tab + (size_t)row * FH + (l & 1) * 8;
      gload_lds16(g, swv + r * 512 + l * 8);
    }
    asm volatile("s_waitcnt vmcnt(0)" ::: "memory");
    __builtin_amdgcn_sched_barrier(0);
#pragma unroll
    for (int r = 0; r < 4; ++r) {
      if (!vld[r]) continue;
      const uint4 q = *(const uint4*)(swv + r * 512 + l * 8);  // ds_read_b128
      float* arow = acc + (pk[r] >> SRC_BITS) * AP + (l & 1) * 8;
      float2 f;
      f = __half22float2(*(const __half2*)&q.x); atomicAdd(arow + 0, f.x); atomicAdd(arow + 1, f.y);
      f = __half22float2(*(const __half2*)&q.y); atomicAdd(arow + 2, f.x); atomicAdd(arow + 3, f.y);
      f = __half22float2(*(const __half2*)&q.z); atomicAdd(arow + 4, f.x); atomicAdd(arow + 5, f.y);
      f = __half22float2(*(const __half2*)&q.w); atomicAdd(arow + 6, f.x); atomicAdd(arow + 7, f.y);
    }
  }
}

// ---------- layer-1 gather ----------
__global__ __launch_bounds__(512) void gather1_k(const __half* __restrict__ hs1,
                                                 const unsigned* __restrict__ boff,
                                                 const unsigned* __restrict__ bins,
                                                 const float* __restrict__ dinv,
                                                 const float* __restrict__ b1, int n,
                                                 __half* __restrict__ rs) {
  __shared__ float acc[RANGE * AP];             // 8.7 KiB
  __shared__ __half stage[8 * WED * FH];        // 32 KiB
  __shared__ float b1s[FH];
  const int t = threadIdx.x, b = blockIdx.x;
  if (t < FH) b1s[t] = b1[t];
  for (int u = t; u < RANGE * AP; u += 512) acc[u] = 0.f;
  __syncthreads();
  const unsigned jb = boff[b], je = boff[b + 1];
  edge_phase(hs1, bins, jb, je, t, stage, acc);
  __syncthreads();
  const int base = b * RANGE;
  {
    const int node = t >> 2, sub = t & 3;  // 512 threads -> 128 nodes x 4 chunks
    const int i = base + node;
    if (i < n) {
      const float* arow = acc + node * AP + sub * 4;
      const float a0 = arow[0], a1 = arow[1], a2 = arow[2], a3 = arow[3];
      const __half2* hp = (const __half2*)(hs1 + (size_t)i * FH + sub * 4);
      const float2 h0 = __half22float2(hp[0]);
      const float2 h1 = __half22float2(hp[1]);
      const float d = dinv[i];
      float r0 = (a0 + h0.x) * d + b1s[sub * 4 + 0];
      float r1 = (a1 + h0.y) * d + b1s[sub * 4 + 1];
      float r2 = (a2 + h1.x) * d + b1s[sub * 4 + 2];
      float r3 = (a3 + h1.y) * d + b1s[sub * 4 + 3];
      r0 = fmaxf(r0, 0.f) * d;
      r1 = fmaxf(r1, 0.f) * d;
      r2 = fmaxf(r2, 0.f) * d;
      r3 = fmaxf(r3, 0.f) * d;
      __half2* rp = (__half2*)(rs + (size_t)i * FH + sub * 4);
      rp[0] = __floats2half2_rn(r0, r1);
      rp[1] = __floats2half2_rn(r2, r3);
    }
  }
}

// ---- layer-2: async gather + W2 matvec + b2 + log_softmax ----
__global__ __launch_bounds__(512) void gather2_k(const __half* __restrict__ rs,
                                                 const unsigned* __restrict__ boff,
                                                 const unsigned* __restrict__ bins,
                                                 const float* __restrict__ dinv,
                                                 const float* __restrict__ W2,
                                                 const float* __restrict__ b2, int n,
                                                 float* __restrict__ out) {
  __shared__ float acc[RANGE * AP];             // 8.7 KiB
  __shared__ __half stage[8 * WED * FH];        // 32 KiB
  __shared__ float w2s[FH * FOUT + FOUT];       // W2 then b2
  const int t = threadIdx.x, b = blockIdx.x;
  for (int idx = t; idx < FH * FOUT + FOUT; idx += 512)
    w2s[idx] = (idx < FH * FOUT) ? W2[idx] : b2[idx - FH * FOUT];
  for (int u = t; u < RANGE * AP; u += 512) acc[u] = 0.f;
  __syncthreads();
  const unsigned jb = boff[b], je = boff[b + 1];
  edge_phase(rs, bins, jb, je, t, stage, acc);
  __syncthreads();
  const int base = b * RANGE;
  // phase 1: acc = (acc + rs_self) * dinv
  {
    const int node = t >> 2, sub = t & 3;
    const int i = base + node;
    if (i < n) {
      float* arow = acc + node * AP + sub * 4;
      const __half2* rp = (const __half2*)(rs + (size_t)i * FH + sub * 4);
      const float2 r0 = __half22float2(rp[0]);
      const float2 r1 = __half22float2(rp[1]);
      const float d = dinv[i];
      arow[0] = (arow[0] + r0.x) * d;
      arow[1] = (arow[1] + r0.y) * d;
      arow[2] = (arow[2] + r1.x) * d;
      arow[3] = (arow[3] + r1.y) * d;
    }
  }
  __syncthreads();
  // phase 2: per-node 16->40 matvec + log_softmax (8 waves, nodes round-robin)
  const int lane = t & 63, wv = t >> 6;
  for (int nd = wv; nd < RANGE; nd += 8) {
    const int i = base + nd;
    if (i >= n) continue;
    float hv = (lane < FOUT) ? w2s[FH * FOUT + lane] : 0.f;
#pragma unroll
    for (int kk = 0; kk < 16; ++kk) {
      const float a = acc[nd * AP + kk];  // LDS broadcast
      if (lane < FOUT) hv += a * w2s[kk * FOUT + lane];
    }
    float m = (lane < FOUT) ? hv : -INFINITY;
#pragma unroll
    for (int d = 1; d < 64; d <<= 1) m = fmaxf(m, __shfl_xor(m, d));
    float ex = (lane < FOUT) ? expf(hv - m) : 0.f;
#pragma unroll
    for (int d = 1; d < 64; d <<= 1) ex += __shfl_xor(ex, d);
    if (lane < FOUT) out[(size_t)i * FOUT + lane] = hv - m - logf(ex);
  }
}

// ---------------- launch ----------------
extern "C" void kernel_launch(void* const* d_in, const int* in_sizes, int n_in,
                              void* d_out, int out_size, void* d_ws, size_t ws_size,
                              hipStream_t stream) {
  const float* x  = (const float*)d_in[0];
  const int*   ei = (const int*)d_in[1];
  const float* W1 = (const float*)d_in[2];
  const float* b1 = (const float*)d_in[3];
  const float* W2 = (const float*)d_in[4];
  const float* b2 = (const float*)d_in[5];
  float* out = (float*)d_out;

  const int n = in_sizes[0] / FIN;
  const int E = in_sizes[1] / 2;
  const int* src = ei;
  const int* dst = ei + E;
  const int NB = (n + RANGE - 1) >> RSH;

  char* ws = (char*)d_ws;
  size_t o = 0;
  auto alloc = [&](size_t bytes) {
    void* p = ws + o;
    o = (o + bytes + 255) & ~(size_t)255;
    return p;
  };
  unsigned* bcnt = (unsigned*)alloc((size_t)(NB + 1) * 4);
  unsigned* boff = (unsigned*)alloc((size_t)(NB + 1) * 4);
  unsigned* bcur = (unsigned*)alloc((size_t)NB * 4);
  float*    dinv = (float*)alloc((size_t)n * 4);
  unsigned* bins = (unsigned*)alloc((size_t)E * 4);
  __half*   hs1  = (__half*)alloc((size_t)n * FH * 2);
  __half*   rsb  = (__half*)alloc((size_t)n * FH * 2);

  hipMemsetAsync(bcnt, 0, (size_t)(NB + 1) * 4, stream);

  histA_k<<<(E + HCHUNK - 1) / HCHUNK, 256, 0, stream>>>(dst, E, NB, bcnt);
  scanB_k<<<1, 1024, 0, stream>>>(bcnt, NB, boff, bcur);
  bin_k<<<(E + BCHUNK - 1) / BCHUNK, 256, 0, stream>>>(src, dst, E, NB, bcur, bins);
  deg_k<<<NB, 256, 0, stream>>>(boff, bins, n, dinv);

  gemm1_k<<<(n + 255) / 256, 256, 0, stream>>>(x, W1, dinv, n, hs1);
  gather1_k<<<NB, 512, 0, stream>>>(hs1, boff, bins, dinv, b1, n, rsb);
  gather2_k<<<NB, 512, 0, stream>>>(rsb, boff, bins, dinv, W2, b2, n, out);
}